// Round 11
// baseline (316.104 us; speedup 1.0000x reference)
//
#include <hip/hip_runtime.h>
#include <math.h>

#define BB 32
#define NN 2048
#define D_IN 320
#define H1 160
#define H2 80
#define H4 5

typedef __attribute__((ext_vector_type(8))) short short8;
typedef __attribute__((ext_vector_type(4))) short short4v;
typedef __attribute__((ext_vector_type(4))) float f32x4;
typedef __attribute__((ext_vector_type(16))) float f32x16;

__device__ inline ushort f2bf(float f) {
    union { float f; unsigned u; } v; v.f = f;
    unsigned r = v.u + 0x7fff + ((v.u >> 16) & 1);   // RNE
    return (ushort)(r >> 16);
}
__device__ inline float bf2f(ushort u) {
    union { float f; unsigned u; } v; v.u = ((unsigned)u) << 16;
    return v.f;
}
// pack 2 floats -> 2 bf16 in one dword (lo in low half): round-half-up + v_perm
__device__ inline unsigned pkbf(float hi, float lo) {
    union { float f; unsigned u; } a, b; a.f = hi; b.f = lo;
    return __builtin_amdgcn_perm(a.u + 0x8000u, b.u + 0x8000u, 0x07060302u);
}
union U2S { unsigned u[2]; short4v s; };
union U4S { unsigned u[4]; short8 s; short4v h[2]; };

#define LOG2E  1.44269504088896340736f
#define TWOL2E 2.88539008177792681472f

// ---------------------------------------------------------------------------
// Prep: bf16-transpose weights. Wt1[160][320], Wt2[80][160].
// Wg1T[64][96] / Wg2T[32][64]: zero-padded AND channel-permuted within each
// 16-group (pos = (c&3) + 4*((c>>3)&1) + 8*((c>>2)&1)) so the conv projection
// A-operand is a single b128 read. bg1P[64], bg2P[32] zero-padded.
// ---------------------------------------------------------------------------
__global__ __launch_bounds__(256) void prep_weights_kernel(
    const float* __restrict__ W1, const float* __restrict__ W2,
    const float* __restrict__ Wg1, const float* __restrict__ bg1,
    const float* __restrict__ Wg2, const float* __restrict__ bg2,
    ushort* __restrict__ Wt1, ushort* __restrict__ Wt2,
    ushort* __restrict__ Wg1T, float* __restrict__ bg1P,
    ushort* __restrict__ Wg2T, float* __restrict__ bg2P)
{
    const int id0 = blockIdx.x * 256 + threadIdx.x;
    const int stride = gridDim.x * 256;
    for (int i = id0; i < H1 * D_IN; i += stride) {
        const int j = i / D_IN, c = i % D_IN;
        Wt1[i] = f2bf(W1[c * H1 + j]);
    }
    for (int i = id0; i < H2 * H1; i += stride) {
        const int j = i / H1, c = i % H1;
        Wt2[i] = f2bf(W2[c * H2 + j]);
    }
    for (int i = id0; i < 64 * 96; i += stride) {
        const int j = i / 96, c = i % 96;
        const int c4 = c & 15;
        const int pos = (c & ~15) + (c4 & 3) + (((c4 >> 3) & 1) << 2) + (((c4 >> 2) & 1) << 3);
        Wg1T[j * 96 + pos] = (j < 40 && c < 80) ? f2bf(Wg1[c * 40 + j]) : (ushort)0;
    }
    for (int i = id0; i < 32 * 64; i += stride) {
        const int j = i / 64, c = i % 64;
        const int c4 = c & 15;
        const int pos = (c & ~15) + (c4 & 3) + (((c4 >> 3) & 1) << 2) + (((c4 >> 2) & 1) << 3);
        Wg2T[j * 64 + pos] = (j < 5 && c < 40) ? f2bf(Wg2[c * 5 + j]) : (ushort)0;
    }
    if (id0 < 64) bg1P[id0] = (id0 < 40) ? bg1[id0] : 0.f;
    if (id0 < 32) bg2P[id0] = (id0 < 5) ? bg2[id0] : 0.f;
}

// ---------------------------------------------------------------------------
// MFMA MLP (unchanged from R10): h2 = relu(relu(x@W1+b1)@W2+b2), XCD-swizzled.
// h2 stride 80; h2T [b][96][N] with channel 80 = bf16 1.0; sq2 = |h2|^2*log2e.
// ---------------------------------------------------------------------------
__global__ __launch_bounds__(256) void mlp_mfma_kernel(
    const float* __restrict__ x,
    const ushort* __restrict__ Wt1, const float* __restrict__ b1,
    const ushort* __restrict__ Wt2, const float* __restrict__ b2,
    ushort* __restrict__ h2, ushort* __restrict__ h2T, float* __restrict__ sq2)
{
    constexpr int XST  = 72;
    constexpr int W1ST = 72;
    constexpr int H1ST = 168;

    __shared__ __attribute__((aligned(16))) ushort h1t[64 * H1ST];  // aliases xs
    __shared__ __attribute__((aligned(16))) ushort ws1[H1 * W1ST];  // aliases Tbuf
    __shared__ float b1s[H1];
    __shared__ float b2s[H2];

    ushort* xs = h1t;

    const int t = threadIdx.x;
    const int lane = t & 63, w = t >> 6;
    const int colid = lane & 15, quad = lane >> 4;
    const int i = blockIdx.x;
    const int b = ((i & 7) << 2) + ((i >> 3) & 3);
    const int n0 = (i >> 5) * 64;
    const int row0 = b * NN + n0;

    if (t < H1) b1s[t] = b1[t];
    if (t < H2) b2s[t] = b2[t];

    f32x4 c1[10];
    #pragma unroll
    for (int ns = 0; ns < 10; ++ns) c1[ns] = (f32x4){0.f, 0.f, 0.f, 0.f};

    float4 xr[4];
    short8 wr[5];
    {
        #pragma unroll
        for (int i2 = 0; i2 < 4; ++i2) {
            const int id = t + i2 * 256, row = id >> 4, c4 = id & 15;
            xr[i2] = *(const float4*)&x[(size_t)(row0 + row) * D_IN + c4 * 4];
        }
        #pragma unroll
        for (int i2 = 0; i2 < 5; ++i2) {
            const int id = t + i2 * 256, j = id >> 3, part = id & 7;
            wr[i2] = *(const short8*)&Wt1[j * D_IN + part * 8];
        }
    }

    for (int kc = 0; kc < 5; ++kc) {
        if (kc) __syncthreads();
        #pragma unroll
        for (int i2 = 0; i2 < 4; ++i2) {
            const int id = t + i2 * 256, row = id >> 4, c4 = id & 15;
            uint2 up;
            up.x = pkbf(xr[i2].y, xr[i2].x);
            up.y = pkbf(xr[i2].w, xr[i2].z);
            *(uint2*)&xs[row * XST + c4 * 4] = up;
        }
        #pragma unroll
        for (int i2 = 0; i2 < 5; ++i2) {
            const int id = t + i2 * 256, j = id >> 3, part = id & 7;
            *(short8*)&ws1[j * W1ST + part * 8] = wr[i2];
        }
        __syncthreads();
        if (kc < 4) {
            const int k0 = (kc + 1) * 64;
            #pragma unroll
            for (int i2 = 0; i2 < 4; ++i2) {
                const int id = t + i2 * 256, row = id >> 4, c4 = id & 15;
                xr[i2] = *(const float4*)&x[(size_t)(row0 + row) * D_IN + k0 + c4 * 4];
            }
            #pragma unroll
            for (int i2 = 0; i2 < 5; ++i2) {
                const int id = t + i2 * 256, j = id >> 3, part = id & 7;
                wr[i2] = *(const short8*)&Wt1[j * D_IN + k0 + part * 8];
            }
        }

        short8 af[2];
        #pragma unroll
        for (int kf = 0; kf < 2; ++kf)
            af[kf] = *(const short8*)&xs[(w * 16 + colid) * XST + kf * 32 + quad * 8];
        #pragma unroll
        for (int ns = 0; ns < 10; ++ns) {
            #pragma unroll
            for (int kf = 0; kf < 2; ++kf) {
                const short8 bf = *(const short8*)&ws1[(ns * 16 + colid) * W1ST + kf * 32 + quad * 8];
                c1[ns] = __builtin_amdgcn_mfma_f32_16x16x32_bf16(af[kf], bf, c1[ns], 0, 0, 0);
            }
        }
    }
    __syncthreads();                            // xs dead -> h1t reuse

    #pragma unroll
    for (int ns = 0; ns < 10; ++ns) {
        const float bj = b1s[ns * 16 + colid];
        #pragma unroll
        for (int r = 0; r < 4; ++r)
            h1t[(w * 16 + quad * 4 + r) * H1ST + ns * 16 + colid] =
                f2bf(fmaxf(c1[ns][r] + bj, 0.f));
    }
    __asm__ volatile("s_waitcnt lgkmcnt(0)" ::: "memory");  // wave-private rows

    short8 a2[5];
    #pragma unroll
    for (int kf = 0; kf < 5; ++kf)
        a2[kf] = *(const short8*)&h1t[(w * 16 + colid) * H1ST + kf * 32 + quad * 8];

    f32x4 c2[5];
    #pragma unroll
    for (int js = 0; js < 5; ++js) {
        f32x4 acc = (f32x4){0.f, 0.f, 0.f, 0.f};
        #pragma unroll
        for (int kf = 0; kf < 5; ++kf) {
            const short8 wb = *(const short8*)&Wt2[(js * 16 + colid) * H1 + kf * 32 + quad * 8];
            acc = __builtin_amdgcn_mfma_f32_16x16x32_bf16(a2[kf], wb, acc, 0, 0, 0);
        }
        c2[js] = acc;
    }
    __syncthreads();                            // h1t/ws1 dead -> Tbuf reuse

    ushort* Tbuf = ws1;                         // [96][72]
    float rsq[4] = {0.f, 0.f, 0.f, 0.f};
    #pragma unroll
    for (int js = 0; js < 5; ++js) {
        const float bj = b2s[js * 16 + colid];
        #pragma unroll
        for (int r = 0; r < 4; ++r) {
            const ushort u = f2bf(fmaxf(c2[js][r] + bj, 0.f));
            const float vv = bf2f(u);
            rsq[r] += vv * vv;
            h2[(size_t)(row0 + w * 16 + quad * 4 + r) * 80 + js * 16 + colid] = u;
            Tbuf[(js * 16 + colid) * 72 + w * 16 + quad * 4 + r] = u;
        }
    }
    {   // Tbuf rows 80..95: ones-channel at 80, zeros elsewhere
        const short8 z8 = {0, 0, 0, 0, 0, 0, 0, 0};
        const short8 ones8 = {16256, 16256, 16256, 16256, 16256, 16256, 16256, 16256};
        if (t < 128) {
            const int row = 80 + (t >> 3), part = t & 7;
            *(short8*)&Tbuf[row * 72 + part * 8] = (row == 80) ? ones8 : z8;
        }
    }
    #pragma unroll
    for (int m = 1; m <= 8; m <<= 1)
        #pragma unroll
        for (int r = 0; r < 4; ++r) rsq[r] += __shfl_xor(rsq[r], m);
    if (colid == 0) {
        #pragma unroll
        for (int r = 0; r < 4; ++r)
            sq2[(size_t)row0 + w * 16 + quad * 4 + r] = rsq[r] * LOG2E;
    }
    __syncthreads();
    for (int id = t; id < 96 * 8; id += 256) {
        const int row = id >> 3, part = id & 7;
        *(short8*)&h2T[((size_t)b * 96 + row) * NN + n0 + part * 8] =
            *(const short8*)&Tbuf[row * 72 + part * 8];
    }
}

// ---------------------------------------------------------------------------
// Flash-attention graph conv, 32x32x16 MFMA, 4 waves x 32 q = 128 q/block.
// DOUBLE-BUFFERED K/V/sq tiles: ONE __syncthreads per 64-key iteration.
// V stored in LDS with the phi key-permutation baked in -> PV A-operand is a
// single b128 read; projection weights pre-permuted in prep likewise.
// Ones-channel (ONES_CH) gives the softmax denominator inside PV.
// XCD swizzle keeps each batch's K/V stream L2-resident. sqg pre-scaled.
// ---------------------------------------------------------------------------
template<int CK, int CV, int C_OUT, int JT, int ONES_CH, bool HAS_OUT, bool DO_MEAN>
__global__ __launch_bounds__(256) void attn_conv_kernel(
    const ushort* __restrict__ h, const ushort* __restrict__ hT,
    const float* __restrict__ sqg,
    const ushort* __restrict__ WtG, const float* __restrict__ biasP,
    ushort* __restrict__ ho, ushort* __restrict__ hoT, float* __restrict__ sqo,
    float* __restrict__ mean_out)
{
    constexpr int CFP  = CV / 16;        // projection k-chunks (6 / 4)
    constexpr int CF   = CK / 16;        // S-phase k-chunks (5 / 3)
    constexpr int CSV  = CV / 32;        // PV channel tiles (3 / 2)
    constexpr int KST  = CK + 8;         // 88 / 56
    constexpr int VST  = 64 + 8;         // 72
    constexpr int KPR  = CK / 8;
    constexpr int KTOT = 64 * KPR;
    constexpr int NK   = (KTOT + 255) / 256;
    constexpr int NV   = (CV * 8) / 256;
    constexpr int TST  = 136;
    constexpr int CS1  = ONES_CH / 32;
    constexpr int R1   = ((ONES_CH % 32) / 8) * 4 + (ONES_CH & 3);
    constexpr int BUFN = 64 * KST + CV * VST;

    __shared__ __attribute__((aligned(16))) ushort ldsbuf[2][BUFN];
    __shared__ __attribute__((aligned(16))) float sqs[2][64];

    const int t = threadIdx.x;
    const int lane = t & 63, w = t >> 6;
    const int m32 = lane & 31, hl = lane >> 5;
    const int i = blockIdx.x;
    const int b = ((i & 7) << 2) + ((i >> 3) & 3);
    const int n0blk = (i >> 5) * 128;
    const int qrow = n0blk + w * 32 + m32;

    // Q B-operand frags
    short8 qf[CF];
    {
        const ushort* qr = h + ((size_t)b * NN + qrow) * CK;
        #pragma unroll
        for (int c = 0; c < CF; ++c)
            qf[c] = *(const short8*)&qr[c * 16 + hl * 8];
    }
    const float nsqnQL = -sqg[(size_t)b * NN + qrow];

    f32x16 o[CSV];
    #pragma unroll
    for (int cs = 0; cs < CSV; ++cs)
        #pragma unroll
        for (int r = 0; r < 16; ++r) o[cs][r] = 0.f;

    short8 kreg[NK], vreg[NV];
    float sqreg = 0.f;

    auto loadTile = [&](int n1) {
        const ushort* hsrc = h + ((size_t)b * NN + n1) * CK;
        #pragma unroll
        for (int i2 = 0; i2 < NK; ++i2) {
            const int id = t + i2 * 256;
            if (KTOT % 256 == 0 || id < KTOT)
                kreg[i2] = *(const short8*)&hsrc[id * 8];
        }
        #pragma unroll
        for (int i2 = 0; i2 < NV; ++i2) {
            const int id = t + i2 * 256, c = id >> 3, pt = id & 7;
            vreg[i2] = *(const short8*)&hT[((size_t)b * CV + c) * NN + n1 + pt * 8];
        }
        if (t < 64) sqreg = sqg[(size_t)b * NN + n1 + t];
    };
    auto stageTile = [&](int buf) {
        ushort* Kd = ldsbuf[buf];
        ushort* Vd = ldsbuf[buf] + 64 * KST;
        #pragma unroll
        for (int i2 = 0; i2 < NK; ++i2) {
            const int id = t + i2 * 256;
            if (KTOT % 256 == 0 || id < KTOT) {
                const int row = id / KPR, pt = id % KPR;
                *(short8*)&Kd[row * KST + pt * 8] = kreg[i2];
            }
        }
        #pragma unroll
        for (int i2 = 0; i2 < NV; ++i2) {
            const int id = t + i2 * 256, c = id >> 3, pt = id & 7;
            const int colb = ((pt >> 1) << 4) + ((pt & 1) << 2);  // phi baked in
            U4S vv; vv.s = vreg[i2];
            *(short4v*)&Vd[c * VST + colb]     = vv.h[0];
            *(short4v*)&Vd[c * VST + colb + 8] = vv.h[1];
        }
        if (t < 64) sqs[buf][t] = sqreg;
    };

    loadTile(0);
    stageTile(0);
    __syncthreads();                           // buf0 visible
    loadTile(64);

    for (int it = 0; it < NN / 64; ++it) {
        const int cur = it & 1;
        if (it + 1 < NN / 64) {
            stageTile(cur ^ 1);                // tile it+1 into idle buffer
            if (it + 2 < NN / 64) loadTile((it + 2) * 64);
        }
        const ushort* Krow = ldsbuf[cur];
        const ushort* Vcol = ldsbuf[cur] + 64 * KST;

        #pragma unroll
        for (int T = 0; T < 2; ++T) {
            // S^T: A = K rows (key = 32T + m32), B = Q
            f32x16 st;
            #pragma unroll
            for (int r = 0; r < 16; ++r) st[r] = 0.f;
            #pragma unroll
            for (int c = 0; c < CF; ++c) {
                const short8 af = *(const short8*)&Krow[(T * 32 + m32) * KST + c * 16 + hl * 8];
                st = __builtin_amdgcn_mfma_f32_32x32x16_bf16(af, qf[c], st, 0, 0, 0);
            }
            // reg r: physical key = 32T + (r&3) + 8*(r>>2) + 4*hl
            float p[16];
            #pragma unroll
            for (int g = 0; g < 4; ++g) {
                const f32x4 smv = *(const f32x4*)&sqs[cur][T * 32 + g * 8 + hl * 4];
                #pragma unroll
                for (int r2 = 0; r2 < 4; ++r2)
                    p[g * 4 + r2] = exp2f(fmaf(st[g * 4 + r2], TWOL2E,
                                               nsqnQL - smv[r2]));
            }
            // PV; V layout is phi-permuted -> single b128 A-operand read.
            #pragma unroll
            for (int c = 0; c < 2; ++c) {
                U4S pk_;
                #pragma unroll
                for (int bq = 0; bq < 4; ++bq)
                    pk_.u[bq] = pkbf(p[c * 8 + bq * 2 + 1], p[c * 8 + bq * 2]);
                const int kb = (T * 2 + c) * 16 + hl * 8;
                #pragma unroll
                for (int cs = 0; cs < CSV; ++cs) {
                    const short8 va = *(const short8*)&Vcol[(cs * 32 + m32) * VST + kb];
                    o[cs] = __builtin_amdgcn_mfma_f32_32x32x16_bf16(va, pk_.s, o[cs], 0, 0, 0);
                }
            }
        }
        __syncthreads();                       // reads of buf[cur] done
    }

    // denominator from the ones-channel accumulator (lane hl=0 holds it)
    float rsv = (hl == 0) ? o[CS1][R1] : 0.f;
    rsv += __shfl_xor(rsv, 32);
    const float rinv = 1.f / rsv;

    // O^T C-layout -> projection B-operand frags (phi-consistent, in-register)
    short8 ob[CFP];
    #pragma unroll
    for (int cs = 0; cs < CSV; ++cs)
        #pragma unroll
        for (int c2 = 0; c2 < 2; ++c2) {
            U4S ob_;
            #pragma unroll
            for (int bq = 0; bq < 4; ++bq)
                ob_.u[bq] = pkbf(o[cs][c2 * 8 + bq * 2 + 1] * rinv,
                                 o[cs][c2 * 8 + bq * 2] * rinv);
            ob[cs * 2 + c2] = ob_.s;
        }

    ushort* Tbuf = (ushort*)ldsbuf;            // [64][TST]
    float rsq = 0.f;
    float msum[4] = {0.f, 0.f, 0.f, 0.f};

    #pragma unroll
    for (int jt = 0; jt < JT; ++jt) {
        f32x16 acc;
        #pragma unroll
        for (int r = 0; r < 16; ++r) acc[r] = 0.f;
        #pragma unroll
        for (int cc = 0; cc < CFP; ++cc) {
            // WtG pre-permuted -> single b128 A-operand read
            const short8 wa = *(const short8*)&WtG[(size_t)(jt * 32 + m32) * CV + cc * 16 + hl * 8];
            acc = __builtin_amdgcn_mfma_f32_32x32x16_bf16(wa, ob[cc], acc, 0, 0, 0);
        }
        // reg r: j' = jt*32 + (r&3) + 8*(r>>2) + 4*hl ; col = qrow = m32
        #pragma unroll
        for (int g = 0; g < 4; ++g) {
            const f32x4 bv = *(const f32x4*)&biasP[jt * 32 + g * 8 + hl * 4];
            float v[4];
            #pragma unroll
            for (int r2 = 0; r2 < 4; ++r2) {
                v[r2] = fmaxf(acc[g * 4 + r2] + bv[r2], 0.f);
                rsq += v[r2] * v[r2];
            }
            if (HAS_OUT) {
                U2S uo;
                uo.u[0] = pkbf(v[1], v[0]);
                uo.u[1] = pkbf(v[3], v[2]);
                const int jb = jt * 32 + g * 8 + hl * 4;
                if (jb < 48)                   // ho stored at stride 48
                    *(short4v*)&ho[((size_t)b * NN + qrow) * 48 + jb] = uo.s;
                const int qc = w * 32 + m32;
                #pragma unroll
                for (int r2 = 0; r2 < 4; ++r2)
                    Tbuf[(jb + r2) * TST + qc] =
                        (ushort)(uo.u[r2 >> 1] >> ((r2 & 1) * 16));
            }
            if (DO_MEAN && jt == 0 && g == 0) {
                #pragma unroll
                for (int r2 = 0; r2 < 4; ++r2) msum[r2] = v[r2];
            }
        }
    }

    if (HAS_OUT) {
        const float rsq2 = rsq + __shfl_xor(rsq, 32);
        if (hl == 0) sqo[(size_t)b * NN + qrow] = rsq2 * LOG2E;
        __syncthreads();
        // transposed store: hoT[b][j'][n]; ones-channel substituted at row 40
        const short8 ones8 = {16256, 16256, 16256, 16256, 16256, 16256, 16256, 16256};
        for (int id = t; id < 64 * 16; id += 256) {
            const int row = id >> 4, part = id & 15;
            const short8 val = (row == 40) ? ones8
                             : *(const short8*)&Tbuf[row * TST + part * 8];
            *(short8*)&hoT[((size_t)b * 64 + row) * NN + n0blk + part * 8] = val;
        }
    }
    if (DO_MEAN) {
        #pragma unroll
        for (int s = 1; s <= 16; s <<= 1)
            #pragma unroll
            for (int r2 = 0; r2 < 4; ++r2) msum[r2] += __shfl_xor(msum[r2], s);
        if (m32 == 0) {
            if (hl == 0) {
                #pragma unroll
                for (int r2 = 0; r2 < 4; ++r2)
                    atomicAdd(&mean_out[b * C_OUT + r2], msum[r2] * (1.f / NN));
            } else {
                atomicAdd(&mean_out[b * C_OUT + 4], msum[0] * (1.f / NN));
            }
        }
    }
}

// ---------------------------------------------------------------------------
// Final classifier + softmax over 2 logits.
// ---------------------------------------------------------------------------
__global__ __launch_bounds__(64) void final_kernel(
    const float* __restrict__ mean, const float* __restrict__ Wf,
    const float* __restrict__ bf, float* __restrict__ out)
{
    const int t = threadIdx.x;
    const int b = t >> 1, k = t & 1;
    float acc = bf[k];
    #pragma unroll
    for (int c = 0; c < H4; ++c) acc += mean[b * H4 + c] * Wf[c * 2 + k];
    const float other = __shfl_xor(acc, 1);
    const float mx = fmaxf(acc, other);
    const float e  = __expf(acc - mx);
    const float eo = __expf(other - mx);
    out[t] = e / (e + eo);
}

extern "C" void kernel_launch(void* const* d_in, const int* in_sizes, int n_in,
                              void* d_out, int out_size, void* d_ws, size_t ws_size,
                              hipStream_t stream) {
    const float* x   = (const float*)d_in[0];
    const float* W1  = (const float*)d_in[1];
    const float* b1  = (const float*)d_in[2];
    const float* W2  = (const float*)d_in[3];
    const float* b2  = (const float*)d_in[4];
    const float* Wg1 = (const float*)d_in[5];
    const float* bg1 = (const float*)d_in[6];
    const float* Wg2 = (const float*)d_in[7];
    const float* bg2 = (const float*)d_in[8];
    const float* Wf  = (const float*)d_in[9];
    const float* bf  = (const float*)d_in[10];

    ushort* h2   = (ushort*)d_ws;                        // [B*N][80] bf16
    ushort* h2T  = h2  + (size_t)BB * NN * 80;           // [B][96][N] (ch80=1)
    float*  sq2  = (float*)(h2T + (size_t)BB * 96 * NN); // [B*N] (* log2e)
    ushort* h3   = (ushort*)(sq2 + (size_t)BB * NN);     // [B*N][48]
    ushort* h3T  = h3  + (size_t)BB * NN * 48;           // [B][64][N] (ch40=1)
    float*  sq3  = (float*)(h3T + (size_t)BB * 64 * NN); // [B*N] (* log2e)
    float*  meanb = sq3 + (size_t)BB * NN;               // [B*5] (+pad to 160)
    ushort* Wt1  = (ushort*)(meanb + 160);               // [160][320]
    ushort* Wt2  = Wt1 + (size_t)H1 * D_IN;              // [80][160]
    ushort* Wg1T = Wt2 + (size_t)H2 * H1;                // [64][96] (perm)
    float*  bg1P = (float*)(Wg1T + 64 * 96);             // [64]
    ushort* Wg2T = (ushort*)(bg1P + 64);                 // [32][64] (perm)
    float*  bg2P = (float*)(Wg2T + 32 * 64);             // [32]

    hipMemsetAsync(meanb, 0, BB * H4 * sizeof(float), stream);

    prep_weights_kernel<<<64, 256, 0, stream>>>(W1, W2, Wg1, bg1, Wg2, bg2,
                                                Wt1, Wt2, Wg1T, bg1P, Wg2T, bg2P);
    mlp_mfma_kernel<<<BB * NN / 64, 256, 0, stream>>>(x, Wt1, b1, Wt2, b2, h2, h2T, sq2);
    attn_conv_kernel<80, 96, 40, 2, 80, true,  false><<<BB * NN / 128, 256, 0, stream>>>(
        h2, h2T, sq2, Wg1T, bg1P, h3, h3T, sq3, nullptr);
    attn_conv_kernel<48, 64, 5, 1, 40, false, true><<<BB * NN / 128, 256, 0, stream>>>(
        h3, h3T, sq3, Wg2T, bg2P, nullptr, nullptr, nullptr, meanb);
    final_kernel<<<1, 64, 0, stream>>>(meanb, Wf, bf, (float*)d_out);
}

// Round 12
// 266.830 us; speedup vs baseline: 1.1847x; 1.1847x over previous
//
#include <hip/hip_runtime.h>
#include <math.h>

#define BB 32
#define NN 2048
#define D_IN 320
#define H1 160
#define H2 80
#define H4 5

typedef __attribute__((ext_vector_type(8))) short short8;
typedef __attribute__((ext_vector_type(4))) short short4v;
typedef __attribute__((ext_vector_type(4))) float f32x4;
typedef __attribute__((ext_vector_type(16))) float f32x16;

__device__ inline ushort f2bf(float f) {
    union { float f; unsigned u; } v; v.f = f;
    unsigned r = v.u + 0x7fff + ((v.u >> 16) & 1);   // RNE
    return (ushort)(r >> 16);
}
__device__ inline float bf2f(ushort u) {
    union { float f; unsigned u; } v; v.u = ((unsigned)u) << 16;
    return v.f;
}
// pack 2 floats -> 2 bf16 in one dword (lo in low half): round-half-up + v_perm
__device__ inline unsigned pkbf(float hi, float lo) {
    union { float f; unsigned u; } a, b; a.f = hi; b.f = lo;
    return __builtin_amdgcn_perm(a.u + 0x8000u, b.u + 0x8000u, 0x07060302u);
}
// bare v_exp_f32: args here are always <= 0; big-negative flushes to 0 (wanted).
__device__ inline float fexp2(float x) {
    float r;
    asm("v_exp_f32 %0, %1" : "=v"(r) : "v"(x));
    return r;
}
union U2S { unsigned u[2]; short4v s; };
union U4S { unsigned u[4]; short8 s; short4v h[2]; };

#define LOG2E  1.44269504088896340736f
#define TWOL2E 2.88539008177792681472f

// ---------------------------------------------------------------------------
// Prep: bf16-transpose weights. Wt1[160][320], Wt2[80][160].
// Wg1T[64][96] / Wg2T[32][64]: zero-padded AND channel-permuted within each
// 16-group (pos = (c&3) + 4*((c>>3)&1) + 8*((c>>2)&1)) so the conv projection
// A-operand is a single b128 read. bg1P[64], bg2P[32] zero-padded.
// ---------------------------------------------------------------------------
__global__ __launch_bounds__(256) void prep_weights_kernel(
    const float* __restrict__ W1, const float* __restrict__ W2,
    const float* __restrict__ Wg1, const float* __restrict__ bg1,
    const float* __restrict__ Wg2, const float* __restrict__ bg2,
    ushort* __restrict__ Wt1, ushort* __restrict__ Wt2,
    ushort* __restrict__ Wg1T, float* __restrict__ bg1P,
    ushort* __restrict__ Wg2T, float* __restrict__ bg2P)
{
    const int id0 = blockIdx.x * 256 + threadIdx.x;
    const int stride = gridDim.x * 256;
    for (int i = id0; i < H1 * D_IN; i += stride) {
        const int j = i / D_IN, c = i % D_IN;
        Wt1[i] = f2bf(W1[c * H1 + j]);
    }
    for (int i = id0; i < H2 * H1; i += stride) {
        const int j = i / H1, c = i % H1;
        Wt2[i] = f2bf(W2[c * H2 + j]);
    }
    for (int i = id0; i < 64 * 96; i += stride) {
        const int j = i / 96, c = i % 96;
        const int c4 = c & 15;
        const int pos = (c & ~15) + (c4 & 3) + (((c4 >> 3) & 1) << 2) + (((c4 >> 2) & 1) << 3);
        Wg1T[j * 96 + pos] = (j < 40 && c < 80) ? f2bf(Wg1[c * 40 + j]) : (ushort)0;
    }
    for (int i = id0; i < 32 * 64; i += stride) {
        const int j = i / 64, c = i % 64;
        const int c4 = c & 15;
        const int pos = (c & ~15) + (c4 & 3) + (((c4 >> 3) & 1) << 2) + (((c4 >> 2) & 1) << 3);
        Wg2T[j * 64 + pos] = (j < 5 && c < 40) ? f2bf(Wg2[c * 5 + j]) : (ushort)0;
    }
    if (id0 < 64) bg1P[id0] = (id0 < 40) ? bg1[id0] : 0.f;
    if (id0 < 32) bg2P[id0] = (id0 < 5) ? bg2[id0] : 0.f;
}

// ---------------------------------------------------------------------------
// MFMA MLP (unchanged from R11): h2 = relu(relu(x@W1+b1)@W2+b2), XCD-swizzled.
// h2 stride 80; h2T [b][96][N] with channel 80 = bf16 1.0; sq2 = |h2|^2*log2e.
// ---------------------------------------------------------------------------
__global__ __launch_bounds__(256) void mlp_mfma_kernel(
    const float* __restrict__ x,
    const ushort* __restrict__ Wt1, const float* __restrict__ b1,
    const ushort* __restrict__ Wt2, const float* __restrict__ b2,
    ushort* __restrict__ h2, ushort* __restrict__ h2T, float* __restrict__ sq2)
{
    constexpr int XST  = 72;
    constexpr int W1ST = 72;
    constexpr int H1ST = 168;

    __shared__ __attribute__((aligned(16))) ushort h1t[64 * H1ST];  // aliases xs
    __shared__ __attribute__((aligned(16))) ushort ws1[H1 * W1ST];  // aliases Tbuf
    __shared__ float b1s[H1];
    __shared__ float b2s[H2];

    ushort* xs = h1t;

    const int t = threadIdx.x;
    const int lane = t & 63, w = t >> 6;
    const int colid = lane & 15, quad = lane >> 4;
    const int i = blockIdx.x;
    const int b = ((i & 7) << 2) + ((i >> 3) & 3);
    const int n0 = (i >> 5) * 64;
    const int row0 = b * NN + n0;

    if (t < H1) b1s[t] = b1[t];
    if (t < H2) b2s[t] = b2[t];

    f32x4 c1[10];
    #pragma unroll
    for (int ns = 0; ns < 10; ++ns) c1[ns] = (f32x4){0.f, 0.f, 0.f, 0.f};

    float4 xr[4];
    short8 wr[5];
    {
        #pragma unroll
        for (int i2 = 0; i2 < 4; ++i2) {
            const int id = t + i2 * 256, row = id >> 4, c4 = id & 15;
            xr[i2] = *(const float4*)&x[(size_t)(row0 + row) * D_IN + c4 * 4];
        }
        #pragma unroll
        for (int i2 = 0; i2 < 5; ++i2) {
            const int id = t + i2 * 256, j = id >> 3, part = id & 7;
            wr[i2] = *(const short8*)&Wt1[j * D_IN + part * 8];
        }
    }

    for (int kc = 0; kc < 5; ++kc) {
        if (kc) __syncthreads();
        #pragma unroll
        for (int i2 = 0; i2 < 4; ++i2) {
            const int id = t + i2 * 256, row = id >> 4, c4 = id & 15;
            uint2 up;
            up.x = pkbf(xr[i2].y, xr[i2].x);
            up.y = pkbf(xr[i2].w, xr[i2].z);
            *(uint2*)&xs[row * XST + c4 * 4] = up;
        }
        #pragma unroll
        for (int i2 = 0; i2 < 5; ++i2) {
            const int id = t + i2 * 256, j = id >> 3, part = id & 7;
            *(short8*)&ws1[j * W1ST + part * 8] = wr[i2];
        }
        __syncthreads();
        if (kc < 4) {
            const int k0 = (kc + 1) * 64;
            #pragma unroll
            for (int i2 = 0; i2 < 4; ++i2) {
                const int id = t + i2 * 256, row = id >> 4, c4 = id & 15;
                xr[i2] = *(const float4*)&x[(size_t)(row0 + row) * D_IN + k0 + c4 * 4];
            }
            #pragma unroll
            for (int i2 = 0; i2 < 5; ++i2) {
                const int id = t + i2 * 256, j = id >> 3, part = id & 7;
                wr[i2] = *(const short8*)&Wt1[j * D_IN + k0 + part * 8];
            }
        }

        short8 af[2];
        #pragma unroll
        for (int kf = 0; kf < 2; ++kf)
            af[kf] = *(const short8*)&xs[(w * 16 + colid) * XST + kf * 32 + quad * 8];
        #pragma unroll
        for (int ns = 0; ns < 10; ++ns) {
            #pragma unroll
            for (int kf = 0; kf < 2; ++kf) {
                const short8 bf = *(const short8*)&ws1[(ns * 16 + colid) * W1ST + kf * 32 + quad * 8];
                c1[ns] = __builtin_amdgcn_mfma_f32_16x16x32_bf16(af[kf], bf, c1[ns], 0, 0, 0);
            }
        }
    }
    __syncthreads();                            // xs dead -> h1t reuse

    #pragma unroll
    for (int ns = 0; ns < 10; ++ns) {
        const float bj = b1s[ns * 16 + colid];
        #pragma unroll
        for (int r = 0; r < 4; ++r)
            h1t[(w * 16 + quad * 4 + r) * H1ST + ns * 16 + colid] =
                f2bf(fmaxf(c1[ns][r] + bj, 0.f));
    }
    __asm__ volatile("s_waitcnt lgkmcnt(0)" ::: "memory");  // wave-private rows

    short8 a2[5];
    #pragma unroll
    for (int kf = 0; kf < 5; ++kf)
        a2[kf] = *(const short8*)&h1t[(w * 16 + colid) * H1ST + kf * 32 + quad * 8];

    f32x4 c2[5];
    #pragma unroll
    for (int js = 0; js < 5; ++js) {
        f32x4 acc = (f32x4){0.f, 0.f, 0.f, 0.f};
        #pragma unroll
        for (int kf = 0; kf < 5; ++kf) {
            const short8 wb = *(const short8*)&Wt2[(js * 16 + colid) * H1 + kf * 32 + quad * 8];
            acc = __builtin_amdgcn_mfma_f32_16x16x32_bf16(a2[kf], wb, acc, 0, 0, 0);
        }
        c2[js] = acc;
    }
    __syncthreads();                            // h1t/ws1 dead -> Tbuf reuse

    ushort* Tbuf = ws1;                         // [96][72]
    float rsq[4] = {0.f, 0.f, 0.f, 0.f};
    #pragma unroll
    for (int js = 0; js < 5; ++js) {
        const float bj = b2s[js * 16 + colid];
        #pragma unroll
        for (int r = 0; r < 4; ++r) {
            const ushort u = f2bf(fmaxf(c2[js][r] + bj, 0.f));
            const float vv = bf2f(u);
            rsq[r] += vv * vv;
            h2[(size_t)(row0 + w * 16 + quad * 4 + r) * 80 + js * 16 + colid] = u;
            Tbuf[(js * 16 + colid) * 72 + w * 16 + quad * 4 + r] = u;
        }
    }
    {   // Tbuf rows 80..95: ones-channel at 80, zeros elsewhere
        const short8 z8 = {0, 0, 0, 0, 0, 0, 0, 0};
        const short8 ones8 = {16256, 16256, 16256, 16256, 16256, 16256, 16256, 16256};
        if (t < 128) {
            const int row = 80 + (t >> 3), part = t & 7;
            *(short8*)&Tbuf[row * 72 + part * 8] = (row == 80) ? ones8 : z8;
        }
    }
    #pragma unroll
    for (int m = 1; m <= 8; m <<= 1)
        #pragma unroll
        for (int r = 0; r < 4; ++r) rsq[r] += __shfl_xor(rsq[r], m);
    if (colid == 0) {
        #pragma unroll
        for (int r = 0; r < 4; ++r)
            sq2[(size_t)row0 + w * 16 + quad * 4 + r] = rsq[r] * LOG2E;
    }
    __syncthreads();
    for (int id = t; id < 96 * 8; id += 256) {
        const int row = id >> 3, part = id & 7;
        *(short8*)&h2T[((size_t)b * 96 + row) * NN + n0 + part * 8] =
            *(const short8*)&Tbuf[row * 72 + part * 8];
    }
}

// ---------------------------------------------------------------------------
// Flash-attention graph conv, 32x32x16 MFMA, 4 waves x 32 q = 128 q/block.
// Double-buffered K/V/sq; ONE barrier per 64-key iteration. ALL LDS fragments
// for the tile are PRELOADED into registers at iteration start (grid caps
// occupancy at 2 waves/SIMD, so VGPRs are free) — ds_read latency overlaps
// the S-MFMA chain instead of serializing before each consumer.
// phi-permuted V/W layouts -> b128 reads; ones-channel denominator; raw
// v_exp_f32; XCD swizzle; sqg pre-scaled by log2e.
// ---------------------------------------------------------------------------
template<int CK, int CV, int C_OUT, int JT, int ONES_CH, bool HAS_OUT, bool DO_MEAN>
__global__ __launch_bounds__(256, 2) void attn_conv_kernel(
    const ushort* __restrict__ h, const ushort* __restrict__ hT,
    const float* __restrict__ sqg,
    const ushort* __restrict__ WtG, const float* __restrict__ biasP,
    ushort* __restrict__ ho, ushort* __restrict__ hoT, float* __restrict__ sqo,
    float* __restrict__ mean_out)
{
    constexpr int CFP  = CV / 16;        // projection k-chunks (6 / 4)
    constexpr int CF   = CK / 16;        // S-phase k-chunks (5 / 3)
    constexpr int CSV  = CV / 32;        // PV channel tiles (3 / 2)
    constexpr int KST  = CK + 8;         // 88 / 56
    constexpr int VST  = 64 + 8;         // 72
    constexpr int KPR  = CK / 8;
    constexpr int KTOT = 64 * KPR;
    constexpr int NK   = (KTOT + 255) / 256;
    constexpr int NV   = (CV * 8) / 256;
    constexpr int TST  = 136;
    constexpr int CS1  = ONES_CH / 32;
    constexpr int R1   = ((ONES_CH % 32) / 8) * 4 + (ONES_CH & 3);
    constexpr int BUFN = 64 * KST + CV * VST;

    __shared__ __attribute__((aligned(16))) ushort ldsbuf[2][BUFN];
    __shared__ __attribute__((aligned(16))) float sqs[2][64];

    const int t = threadIdx.x;
    const int lane = t & 63, w = t >> 6;
    const int m32 = lane & 31, hl = lane >> 5;
    const int i = blockIdx.x;
    const int b = ((i & 7) << 2) + ((i >> 3) & 3);
    const int n0blk = (i >> 5) * 128;
    const int qrow = n0blk + w * 32 + m32;

    // Q B-operand frags
    short8 qf[CF];
    {
        const ushort* qr = h + ((size_t)b * NN + qrow) * CK;
        #pragma unroll
        for (int c = 0; c < CF; ++c)
            qf[c] = *(const short8*)&qr[c * 16 + hl * 8];
    }
    const float nsqnQL = -sqg[(size_t)b * NN + qrow];

    f32x16 o[CSV];
    #pragma unroll
    for (int cs = 0; cs < CSV; ++cs)
        #pragma unroll
        for (int r = 0; r < 16; ++r) o[cs][r] = 0.f;

    short8 kreg[NK], vreg[NV];
    float sqreg = 0.f;

    auto loadTile = [&](int n1) {
        const ushort* hsrc = h + ((size_t)b * NN + n1) * CK;
        #pragma unroll
        for (int i2 = 0; i2 < NK; ++i2) {
            const int id = t + i2 * 256;
            if (KTOT % 256 == 0 || id < KTOT)
                kreg[i2] = *(const short8*)&hsrc[id * 8];
        }
        #pragma unroll
        for (int i2 = 0; i2 < NV; ++i2) {
            const int id = t + i2 * 256, c = id >> 3, pt = id & 7;
            vreg[i2] = *(const short8*)&hT[((size_t)b * CV + c) * NN + n1 + pt * 8];
        }
        if (t < 64) sqreg = sqg[(size_t)b * NN + n1 + t];
    };
    auto stageTile = [&](int buf) {
        ushort* Kd = ldsbuf[buf];
        ushort* Vd = ldsbuf[buf] + 64 * KST;
        #pragma unroll
        for (int i2 = 0; i2 < NK; ++i2) {
            const int id = t + i2 * 256;
            if (KTOT % 256 == 0 || id < KTOT) {
                const int row = id / KPR, pt = id % KPR;
                *(short8*)&Kd[row * KST + pt * 8] = kreg[i2];
            }
        }
        #pragma unroll
        for (int i2 = 0; i2 < NV; ++i2) {
            const int id = t + i2 * 256, c = id >> 3, pt = id & 7;
            const int colb = ((pt >> 1) << 4) + ((pt & 1) << 2);  // phi baked in
            U4S vv; vv.s = vreg[i2];
            *(short4v*)&Vd[c * VST + colb]     = vv.h[0];
            *(short4v*)&Vd[c * VST + colb + 8] = vv.h[1];
        }
        if (t < 64) sqs[buf][t] = sqreg;
    };

    loadTile(0);
    stageTile(0);
    __syncthreads();                           // buf0 visible
    loadTile(64);

    for (int it = 0; it < NN / 64; ++it) {
        const int cur = it & 1;
        const ushort* Krow = ldsbuf[cur];
        const ushort* Vcol = ldsbuf[cur] + 64 * KST;

        // ---- PRELOAD all tile fragments into registers (batched ds_reads) ----
        short8 kf_[2][CF];
        short8 vf_[2][2][CSV];
        f32x4  smv_[2][4];
        #pragma unroll
        for (int T = 0; T < 2; ++T) {
            #pragma unroll
            for (int c = 0; c < CF; ++c)
                kf_[T][c] = *(const short8*)&Krow[(T * 32 + m32) * KST + c * 16 + hl * 8];
            #pragma unroll
            for (int c = 0; c < 2; ++c)
                #pragma unroll
                for (int cs = 0; cs < CSV; ++cs)
                    vf_[T][c][cs] = *(const short8*)&Vcol[(cs * 32 + m32) * VST + (T * 2 + c) * 16 + hl * 8];
            #pragma unroll
            for (int g = 0; g < 4; ++g)
                smv_[T][g] = *(const f32x4*)&sqs[cur][T * 32 + g * 8 + hl * 4];
        }

        if (it + 1 < NN / 64) {
            stageTile(cur ^ 1);                // tile it+1 into idle buffer
            if (it + 2 < NN / 64) loadTile((it + 2) * 64);
        }

        // ---- S^T for both 32-key tiles, interleaved chains ----
        f32x16 st0, st1;
        #pragma unroll
        for (int r = 0; r < 16; ++r) { st0[r] = 0.f; st1[r] = 0.f; }
        #pragma unroll
        for (int c = 0; c < CF; ++c) {
            st0 = __builtin_amdgcn_mfma_f32_32x32x16_bf16(kf_[0][c], qf[c], st0, 0, 0, 0);
            st1 = __builtin_amdgcn_mfma_f32_32x32x16_bf16(kf_[1][c], qf[c], st1, 0, 0, 0);
        }

        // ---- exp + pack + PV (registers only) ----
        #pragma unroll
        for (int T = 0; T < 2; ++T) {
            const f32x16& st = T ? st1 : st0;
            float p[16];
            #pragma unroll
            for (int g = 0; g < 4; ++g) {
                #pragma unroll
                for (int r2 = 0; r2 < 4; ++r2)
                    p[g * 4 + r2] = fexp2(fmaf(st[g * 4 + r2], TWOL2E,
                                               nsqnQL - smv_[T][g][r2]));
            }
            #pragma unroll
            for (int c = 0; c < 2; ++c) {
                U4S pk_;
                #pragma unroll
                for (int bq = 0; bq < 4; ++bq)
                    pk_.u[bq] = pkbf(p[c * 8 + bq * 2 + 1], p[c * 8 + bq * 2]);
                #pragma unroll
                for (int cs = 0; cs < CSV; ++cs)
                    o[cs] = __builtin_amdgcn_mfma_f32_32x32x16_bf16(vf_[T][c][cs], pk_.s, o[cs], 0, 0, 0);
            }
        }
        __syncthreads();                       // reads of buf[cur] done
    }

    // denominator from the ones-channel accumulator (lane hl=0 holds it)
    float rsv = (hl == 0) ? o[CS1][R1] : 0.f;
    rsv += __shfl_xor(rsv, 32);
    const float rinv = 1.f / rsv;

    // O^T C-layout -> projection B-operand frags (phi-consistent, in-register)
    short8 ob[CFP];
    #pragma unroll
    for (int cs = 0; cs < CSV; ++cs)
        #pragma unroll
        for (int c2 = 0; c2 < 2; ++c2) {
            U4S ob_;
            #pragma unroll
            for (int bq = 0; bq < 4; ++bq)
                ob_.u[bq] = pkbf(o[cs][c2 * 8 + bq * 2 + 1] * rinv,
                                 o[cs][c2 * 8 + bq * 2] * rinv);
            ob[cs * 2 + c2] = ob_.s;
        }

    ushort* Tbuf = (ushort*)ldsbuf;            // [64][TST]
    float rsq = 0.f;
    float msum[4] = {0.f, 0.f, 0.f, 0.f};

    #pragma unroll
    for (int jt = 0; jt < JT; ++jt) {
        f32x16 acc;
        #pragma unroll
        for (int r = 0; r < 16; ++r) acc[r] = 0.f;
        #pragma unroll
        for (int cc = 0; cc < CFP; ++cc) {
            // WtG pre-permuted -> single b128 A-operand read
            const short8 wa = *(const short8*)&WtG[(size_t)(jt * 32 + m32) * CV + cc * 16 + hl * 8];
            acc = __builtin_amdgcn_mfma_f32_32x32x16_bf16(wa, ob[cc], acc, 0, 0, 0);
        }
        // reg r: j' = jt*32 + (r&3) + 8*(r>>2) + 4*hl ; col = qrow = m32
        #pragma unroll
        for (int g = 0; g < 4; ++g) {
            const f32x4 bv = *(const f32x4*)&biasP[jt * 32 + g * 8 + hl * 4];
            float v[4];
            #pragma unroll
            for (int r2 = 0; r2 < 4; ++r2) {
                v[r2] = fmaxf(acc[g * 4 + r2] + bv[r2], 0.f);
                rsq += v[r2] * v[r2];
            }
            if (HAS_OUT) {
                U2S uo;
                uo.u[0] = pkbf(v[1], v[0]);
                uo.u[1] = pkbf(v[3], v[2]);
                const int jb = jt * 32 + g * 8 + hl * 4;
                if (jb < 48)                   // ho stored at stride 48
                    *(short4v*)&ho[((size_t)b * NN + qrow) * 48 + jb] = uo.s;
                const int qc = w * 32 + m32;
                #pragma unroll
                for (int r2 = 0; r2 < 4; ++r2)
                    Tbuf[(jb + r2) * TST + qc] =
                        (ushort)(uo.u[r2 >> 1] >> ((r2 & 1) * 16));
            }
            if (DO_MEAN && jt == 0 && g == 0) {
                #pragma unroll
                for (int r2 = 0; r2 < 4; ++r2) msum[r2] = v[r2];
            }
        }
    }

    if (HAS_OUT) {
        const float rsq2 = rsq + __shfl_xor(rsq, 32);
        if (hl == 0) sqo[(size_t)b * NN + qrow] = rsq2 * LOG2E;
        __syncthreads();
        // transposed store: hoT[b][j'][n]; ones-channel substituted at row 40
        const short8 ones8 = {16256, 16256, 16256, 16256, 16256, 16256, 16256, 16256};
        for (int id = t; id < 64 * 16; id += 256) {
            const int row = id >> 4, part = id & 15;
            const short8 val = (row == 40) ? ones8
                             : *(const short8*)&Tbuf[row * TST + part * 8];
            *(short8*)&hoT[((size_t)b * 64 + row) * NN + n0blk + part * 8] = val;
        }
    }
    if (DO_MEAN) {
        #pragma unroll
        for (int s = 1; s <= 16; s <<= 1)
            #pragma unroll
            for (int r2 = 0; r2 < 4; ++r2) msum[r2] += __shfl_xor(msum[r2], s);
        if (m32 == 0) {
            if (hl == 0) {
                #pragma unroll
                for (int r2 = 0; r2 < 4; ++r2)
                    atomicAdd(&mean_out[b * C_OUT + r2], msum[r2] * (1.f / NN));
            } else {
                atomicAdd(&mean_out[b * C_OUT + 4], msum[0] * (1.f / NN));
            }
        }
    }
}

// ---------------------------------------------------------------------------
// Final classifier + softmax over 2 logits.
// ---------------------------------------------------------------------------
__global__ __launch_bounds__(64) void final_kernel(
    const float* __restrict__ mean, const float* __restrict__ Wf,
    const float* __restrict__ bf, float* __restrict__ out)
{
    const int t = threadIdx.x;
    const int b = t >> 1, k = t & 1;
    float acc = bf[k];
    #pragma unroll
    for (int c = 0; c < H4; ++c) acc += mean[b * H4 + c] * Wf[c * 2 + k];
    const float other = __shfl_xor(acc, 1);
    const float mx = fmaxf(acc, other);
    const float e  = __expf(acc - mx);
    const float eo = __expf(other - mx);
    out[t] = e / (e + eo);
}

extern "C" void kernel_launch(void* const* d_in, const int* in_sizes, int n_in,
                              void* d_out, int out_size, void* d_ws, size_t ws_size,
                              hipStream_t stream) {
    const float* x   = (const float*)d_in[0];
    const float* W1  = (const float*)d_in[1];
    const float* b1  = (const float*)d_in[2];
    const float* W2  = (const float*)d_in[3];
    const float* b2  = (const float*)d_in[4];
    const float* Wg1 = (const float*)d_in[5];
    const float* bg1 = (const float*)d_in[6];
    const float* Wg2 = (const float*)d_in[7];
    const float* bg2 = (const float*)d_in[8];
    const float* Wf  = (const float*)d_in[9];
    const float* bf  = (const float*)d_in[10];

    ushort* h2   = (ushort*)d_ws;                        // [B*N][80] bf16
    ushort* h2T  = h2  + (size_t)BB * NN * 80;           // [B][96][N] (ch80=1)
    float*  sq2  = (float*)(h2T + (size_t)BB * 96 * NN); // [B*N] (* log2e)
    ushort* h3   = (ushort*)(sq2 + (size_t)BB * NN);     // [B*N][48]
    ushort* h3T  = h3  + (size_t)BB * NN * 48;           // [B][64][N] (ch40=1)
    float*  sq3  = (float*)(h3T + (size_t)BB * 64 * NN); // [B*N] (* log2e)
    float*  meanb = sq3 + (size_t)BB * NN;               // [B*5] (+pad to 160)
    ushort* Wt1  = (ushort*)(meanb + 160);               // [160][320]
    ushort* Wt2  = Wt1 + (size_t)H1 * D_IN;              // [80][160]
    ushort* Wg1T = Wt2 + (size_t)H2 * H1;                // [64][96] (perm)
    float*  bg1P = (float*)(Wg1T + 64 * 96);             // [64]
    ushort* Wg2T = (ushort*)(bg1P + 64);                 // [32][64] (perm)
    float*  bg2P = (float*)(Wg2T + 32 * 64);             // [32]

    hipMemsetAsync(meanb, 0, BB * H4 * sizeof(float), stream);

    prep_weights_kernel<<<64, 256, 0, stream>>>(W1, W2, Wg1, bg1, Wg2, bg2,
                                                Wt1, Wt2, Wg1T, bg1P, Wg2T, bg2P);
    mlp_mfma_kernel<<<BB * NN / 64, 256, 0, stream>>>(x, Wt1, b1, Wt2, b2, h2, h2T, sq2);
    attn_conv_kernel<80, 96, 40, 2, 80, true,  false><<<BB * NN / 128, 256, 0, stream>>>(
        h2, h2T, sq2, Wg1T, bg1P, h3, h3T, sq3, nullptr);
    attn_conv_kernel<48, 64, 5, 1, 40, false, true><<<BB * NN / 128, 256, 0, stream>>>(
        h3, h3T, sq3, Wg2T, bg2P, nullptr, nullptr, nullptr, meanb);
    final_kernel<<<1, 64, 0, stream>>>(meanb, Wf, bf, (float*)d_out);
}